// Round 1
// 172.479 us; speedup vs baseline: 1.1088x; 1.1088x over previous
//
#include <hip/hip_runtime.h>
#include <hip/hip_bf16.h>
#include <cstdint>
#include <cstddef>

// Problem constants: T=1024, H=1024, I=512, E=16, K=4
#define T_TOK 1024
#define HDIM  1024
#define IDIM  512
#define NEXP  16
#define TOPK  4
#define CAP   1024   // per-expert entry capacity

typedef __bf16 bf16;
typedef __attribute__((ext_vector_type(8))) __bf16 bf16x8;
typedef __attribute__((ext_vector_type(4))) __bf16 bf16x4;
typedef __attribute__((ext_vector_type(4))) float f32x4;

__device__ __forceinline__ void lds_load16(void* lds_dst, const void* g_src) {
  __builtin_amdgcn_global_load_lds(
      (__attribute__((address_space(1))) unsigned int*)(void*)(g_src),
      (__attribute__((address_space(3))) unsigned int*)(lds_dst),
      16, 0, 0);
}

__device__ __forceinline__ bf16x4 cvt4(float4 a) {
  bf16x4 o;
  o[0] = (bf16)a.x; o[1] = (bf16)a.y; o[2] = (bf16)a.z; o[3] = (bf16)a.w;
  return o;
}

// ---------------- fused prep: cvt hid->bf16 (+zero row T) and routing ----------------
// v2: entry lists padded to multiples of 128 (M-tile is now 128).

#define CVT_BLOCKS (T_TOK * HDIM / 4 / 256)   // 1024

__global__ void prep_kernel(const float* __restrict__ hid_f, bf16* __restrict__ hid_b,
                            const int* __restrict__ idx, const float* __restrict__ w,
                            int* __restrict__ etk, float* __restrict__ ew,
                            int* __restrict__ cntpad) {
  __shared__ int cnt;
  const int b = blockIdx.x;
  const int tid = threadIdx.x;
  if (b < CVT_BLOCKS) {
    int i = b * 256 + tid;
    float4 v = ((const float4*)hid_f)[i];
    ((bf16x4*)hid_b)[i] = cvt4(v);
    if (b == 0)  // zero pad row T
      ((bf16x4*)(hid_b + (size_t)T_TOK * HDIM))[tid] = cvt4(make_float4(0.f, 0.f, 0.f, 0.f));
    return;
  }
  const int e = b - CVT_BLOCKS;
  if (tid == 0) cnt = 0;
  __syncthreads();
  for (int j = tid; j < T_TOK * TOPK; j += blockDim.x) {
    if (idx[j] == e) {
      int slot = atomicAdd(&cnt, 1);
      if (slot < CAP) { etk[e * CAP + slot] = j; ew[e * CAP + slot] = w[j]; }
    }
  }
  __syncthreads();
  int c = cnt < CAP ? cnt : CAP;
  int p = (c + 127) & ~127;            // pad to M-tile (128)
  for (int j = c + tid; j < p; j += blockDim.x) {
    etk[e * CAP + j] = (T_TOK << 2);   // points at zeroed row T; kslot 0 -> slab pad row T
    ew[e * CAP + j] = 0.f;
  }
  if (tid == 0) cntpad[e] = p;
}

// ---------------- GEMM1: hsc[entry, i] = silu(g)*u*wgt ----------------
// v2: double-buffered LDS pipeline, ONE barrier per 64-K-step.
// Tile: M=128 (entries) x 32 i-channels (G+U fused), BK=64.
// 4 waves as 2(m)x2(i): wavetile 64x16, 16 MFMA / wave / K-step.
// Loads for k+1 issued before compute on k (A via global_load_lds into the
// alternate buffer; B fp32->regs early, cvt+ds_write late). R5 swizzles kept.
// Grid (16,16,3)=768 blocks, LDS 48KB -> 3 blocks/CU.

__global__ __launch_bounds__(256, 3) void gemm1_kernel(
    const bf16* __restrict__ hid,    // [(T+1),H] bf16, row T zeroed
    const float* __restrict__ gup,   // [E,2I,H] fp32
    const int* __restrict__ etk, const float* __restrict__ ew,
    const int* __restrict__ cntpad,
    bf16* __restrict__ hsc) {        // [E*CAP, I] bf16
  __shared__ __align__(16) bf16 As[2][128 * 64];  // 32 KB
  __shared__ __align__(16) bf16 Bs[2][64 * 64];   // 16 KB (32 G rows + 32 U rows)
  const int e = blockIdx.y, z = blockIdx.z;
  const int ntiles = cntpad[e] >> 7;
  const int n0 = blockIdx.x * 32;    // i-channel base
  const int ebase = e * CAP;
  const int tid = threadIdx.x, lane = tid & 63, wid = tid >> 6;
  const int wm = (wid >> 1) * 64, wi = (wid & 1) * 16;
  const int lcol = lane & 15, lquad = lane >> 4;
  const int l7 = lcol & 7;
  // A async staging: rows srow+32q (q=0..3), source col compensates swizzle
  const int srow = tid >> 3;                 // 0..31
  const int swz = ((tid & 7) ^ (srow & 7)) * 8;
  // B staging: row r=tid>>2 (0..63), 4x float4 at fp32 cols (tid&3)*4 + 16j
  const int r = tid >> 2;
  const int c0 = (tid & 3) * 4;
  const int grow = (r < 32) ? (n0 + r) : (IDIM + n0 + (r - 32));
  const float* gB = gup + (size_t)e * (2 * IDIM) * HDIM + (size_t)grow * HDIM + c0;
  int wb[4];
#pragma unroll
  for (int j = 0; j < 4; ++j) {
    int c = c0 + 16 * j;
    wb[j] = (((c >> 3) ^ (r & 7)) * 8) + (c & 7);
  }
  const int bst = r * 64;

  for (int mt = z; mt < ntiles; mt += 3) {
    const int mrow = ebase + mt * 128;
    const bf16* gA[4];
#pragma unroll
    for (int q = 0; q < 4; ++q)
      gA[q] = hid + (size_t)(etk[mrow + srow + 32 * q] >> 2) * HDIM + swz;
    f32x4 aG[4], aU[4];
#pragma unroll
    for (int mf = 0; mf < 4; ++mf) {
      aG[mf] = f32x4{0.f, 0.f, 0.f, 0.f};
      aU[mf] = f32x4{0.f, 0.f, 0.f, 0.f};
    }
    // prologue: stage k=0 into buffer 0
    {
      float4 bv[4];
#pragma unroll
      for (int j = 0; j < 4; ++j) bv[j] = *(const float4*)(gB + 16 * j);
#pragma unroll
      for (int q = 0; q < 4; ++q)
        lds_load16(&As[0][tid * 8 + q * 2048], gA[q]);
#pragma unroll
      for (int j = 0; j < 4; ++j)
        *(bf16x4*)&Bs[0][bst + wb[j]] = cvt4(bv[j]);
    }
    __syncthreads();
#pragma unroll 2
    for (int k = 0; k < 16; ++k) {
      const int cur = k & 1, nxt = cur ^ 1;
      float4 bn[4];
      if (k < 15) {   // issue k+1 loads FIRST: full iteration of compute cover
#pragma unroll
        for (int q = 0; q < 4; ++q)
          lds_load16(&As[nxt][tid * 8 + q * 2048], gA[q] + (k + 1) * 64);
#pragma unroll
        for (int j = 0; j < 4; ++j)
          bn[j] = *(const float4*)(gB + (k + 1) * 64 + 16 * j);
      }
#pragma unroll
      for (int ks = 0; ks < 2; ++ks) {
        const int lch = ks * 4 + lquad;
        const int sw = (lch ^ l7) * 8;
        bf16x8 bg = *(const bf16x8*)&Bs[cur][(wi + lcol) * 64 + sw];
        bf16x8 bu = *(const bf16x8*)&Bs[cur][(32 + wi + lcol) * 64 + sw];
#pragma unroll
        for (int mf = 0; mf < 4; ++mf) {
          bf16x8 af = *(const bf16x8*)&As[cur][(wm + mf * 16 + lcol) * 64 + sw];
          aG[mf] = __builtin_amdgcn_mfma_f32_16x16x32_bf16(af, bg, aG[mf], 0, 0, 0);
          aU[mf] = __builtin_amdgcn_mfma_f32_16x16x32_bf16(af, bu, aU[mf], 0, 0, 0);
        }
      }
      if (k < 15) {   // late write of B(k+1): load latency hidden under MFMAs
#pragma unroll
        for (int j = 0; j < 4; ++j)
          *(bf16x4*)&Bs[nxt][bst + wb[j]] = cvt4(bn[j]);
      }
      __syncthreads();  // single barrier per K-step: drains A(k+1) lds + B writes
    }
    // epilogue: C/D col=lane&15, row=lquad*4+rr
#pragma unroll
    for (int mf = 0; mf < 4; ++mf) {
#pragma unroll
      for (int rr = 0; rr < 4; ++rr) {
        const int erow = mt * 128 + wm + mf * 16 + lquad * 4 + rr;
        const float wgt = ew[ebase + erow];
        float g = aG[mf][rr], u = aU[mf][rr];
        float s = g / (1.f + __expf(-g));
        hsc[(size_t)(ebase + erow) * IDIM + n0 + wi + lcol] = (bf16)(s * u * wgt);
      }
    }
  }
}

// ---------------- GEMM2: slab[k][tok,h] = hsc[entry,:] . down[e,h,:] ----------------
// Same pipeline. Tile: M=128 x 64 h-channels, BK=64, K=512 (8 steps).
// 4 waves as 2(m)x2(h): wavetile 64x32, 16 MFMA / wave / K-step.

__global__ __launch_bounds__(256, 3) void gemm2_kernel(
    const bf16* __restrict__ hsc,    // [E*CAP, I] bf16
    const float* __restrict__ down,  // [E,H,I] fp32
    const int* __restrict__ etk, const int* __restrict__ cntpad,
    float* __restrict__ slabs) {     // [4][(T+1)][H] fp32
  __shared__ __align__(16) bf16 As[2][128 * 64];  // 32 KB
  __shared__ __align__(16) bf16 Bs[2][64 * 64];   // 16 KB
  const int e = blockIdx.y, z = blockIdx.z;
  const int ntiles = cntpad[e] >> 7;
  const int n0 = blockIdx.x * 64;    // h-channel base
  const int ebase = e * CAP;
  const int tid = threadIdx.x, lane = tid & 63, wid = tid >> 6;
  const int wm = (wid >> 1) * 64, wh = (wid & 1) * 32;
  const int lcol = lane & 15, lquad = lane >> 4;
  const int l7 = lcol & 7;
  const int srow = tid >> 3;
  const int swz = ((tid & 7) ^ (srow & 7)) * 8;
  const int r = tid >> 2;
  const int c0 = (tid & 3) * 4;
  const float* gB = down + (size_t)e * HDIM * IDIM + (size_t)(n0 + r) * IDIM + c0;
  int wb[4];
#pragma unroll
  for (int j = 0; j < 4; ++j) {
    int c = c0 + 16 * j;
    wb[j] = (((c >> 3) ^ (r & 7)) * 8) + (c & 7);
  }
  const int bst = r * 64;

  for (int mt = z; mt < ntiles; mt += 3) {
    const size_t rbase = (size_t)(ebase + mt * 128);
    const bf16* gA[4];
#pragma unroll
    for (int q = 0; q < 4; ++q)
      gA[q] = hsc + (rbase + srow + 32 * q) * IDIM + swz;
    f32x4 acc[4][2];
#pragma unroll
    for (int mf = 0; mf < 4; ++mf) {
      acc[mf][0] = f32x4{0.f, 0.f, 0.f, 0.f};
      acc[mf][1] = f32x4{0.f, 0.f, 0.f, 0.f};
    }
    {
      float4 bv[4];
#pragma unroll
      for (int j = 0; j < 4; ++j) bv[j] = *(const float4*)(gB + 16 * j);
#pragma unroll
      for (int q = 0; q < 4; ++q)
        lds_load16(&As[0][tid * 8 + q * 2048], gA[q]);
#pragma unroll
      for (int j = 0; j < 4; ++j)
        *(bf16x4*)&Bs[0][bst + wb[j]] = cvt4(bv[j]);
    }
    __syncthreads();
#pragma unroll 2
    for (int k = 0; k < 8; ++k) {   // IDIM/64
      const int cur = k & 1, nxt = cur ^ 1;
      float4 bn[4];
      if (k < 7) {
#pragma unroll
        for (int q = 0; q < 4; ++q)
          lds_load16(&As[nxt][tid * 8 + q * 2048], gA[q] + (k + 1) * 64);
#pragma unroll
        for (int j = 0; j < 4; ++j)
          bn[j] = *(const float4*)(gB + (k + 1) * 64 + 16 * j);
      }
#pragma unroll
      for (int ks = 0; ks < 2; ++ks) {
        const int lch = ks * 4 + lquad;
        const int sw = (lch ^ l7) * 8;
        bf16x8 b0 = *(const bf16x8*)&Bs[cur][(wh + lcol) * 64 + sw];
        bf16x8 b1 = *(const bf16x8*)&Bs[cur][(wh + 16 + lcol) * 64 + sw];
#pragma unroll
        for (int mf = 0; mf < 4; ++mf) {
          bf16x8 af = *(const bf16x8*)&As[cur][(wm + mf * 16 + lcol) * 64 + sw];
          acc[mf][0] = __builtin_amdgcn_mfma_f32_16x16x32_bf16(af, b0, acc[mf][0], 0, 0, 0);
          acc[mf][1] = __builtin_amdgcn_mfma_f32_16x16x32_bf16(af, b1, acc[mf][1], 0, 0, 0);
        }
      }
      if (k < 7) {
#pragma unroll
        for (int j = 0; j < 4; ++j)
          *(bf16x4*)&Bs[nxt][bst + wb[j]] = cvt4(bn[j]);
      }
      __syncthreads();
    }
    // epilogue: scatter via etk (pad rows -> slab row T, harmless)
#pragma unroll
    for (int mf = 0; mf < 4; ++mf) {
#pragma unroll
      for (int rr = 0; rr < 4; ++rr) {
        const int row = mt * 128 + wm + mf * 16 + lquad * 4 + rr;
        const int tk = etk[ebase + row];
        const int tok = tk >> 2, ksl = tk & 3;
        float* orow = slabs + ((size_t)ksl * (T_TOK + 1) + tok) * HDIM + n0 + wh + lcol;
        orow[0] = acc[mf][0][rr];
        orow[16] = acc[mf][1][rr];
      }
    }
  }
}

// ---------------- reduce: out = sum of 4 slabs ----------------

__global__ void reduce_kernel(const float* __restrict__ slabs, float* __restrict__ out) {
  const size_t stride = (size_t)(T_TOK + 1) * HDIM;
  int i = blockIdx.x * blockDim.x + threadIdx.x;
  float4 a = ((const float4*)slabs)[i];
  float4 b = ((const float4*)(slabs + stride))[i];
  float4 c = ((const float4*)(slabs + 2 * stride))[i];
  float4 d = ((const float4*)(slabs + 3 * stride))[i];
  float4 o;
  o.x = a.x + b.x + c.x + d.x;
  o.y = a.y + b.y + c.y + d.y;
  o.z = a.z + b.z + c.z + d.z;
  o.w = a.w + b.w + c.w + d.w;
  ((float4*)out)[i] = o;
}

// ---------------- launch ----------------

extern "C" void kernel_launch(void* const* d_in, const int* in_sizes, int n_in,
                              void* d_out, int out_size, void* d_ws, size_t ws_size,
                              hipStream_t stream) {
  const float* hid_f  = (const float*)d_in[0];
  const int*   idx    = (const int*)d_in[1];
  const float* tw     = (const float*)d_in[2];
  const float* gup_f  = (const float*)d_in[3];
  const float* down_f = (const float*)d_in[4];
  float* out = (float*)d_out;

  uint8_t* ws = (uint8_t*)d_ws;
  size_t off = 0;
  bf16* hid_b = (bf16*)(ws + off);   off += (size_t)(T_TOK + 1) * HDIM * 2;
  int*  etk   = (int*)(ws + off);    off += (size_t)NEXP * CAP * 4;
  float* ewt  = (float*)(ws + off);  off += (size_t)NEXP * CAP * 4;
  int* cntpad = (int*)(ws + off);    off += 256;
  bf16* hsc   = (bf16*)(ws + off);   off += (size_t)NEXP * CAP * IDIM * 2;
  float* slabs = (float*)(ws + off); // 4*(T+1)*H*4 ≈ 16.8 MB

  prep_kernel<<<dim3(CVT_BLOCKS + NEXP), dim3(256), 0, stream>>>(
      hid_f, hid_b, idx, tw, etk, ewt, cntpad);
  gemm1_kernel<<<dim3(IDIM / 32, NEXP, 3), dim3(256), 0, stream>>>(
      hid_b, gup_f, etk, ewt, cntpad, hsc);
  gemm2_kernel<<<dim3(HDIM / 64, NEXP, 3), dim3(256), 0, stream>>>(
      hsc, down_f, etk, cntpad, slabs);
  reduce_kernel<<<dim3(T_TOK * HDIM / 4 / 256), dim3(256), 0, stream>>>(slabs, out);
}